// Round 5
// baseline (662.068 us; speedup 1.0000x reference)
//
#include <hip/hip_runtime.h>
#include <hip/hip_bf16.h>

#define NN 100000
#define EE 1600000
#define FF 128
#define HH 128
#define AA 8

typedef unsigned int u32;

__device__ inline u32 packbf2(float a, float b) {
    __hip_bfloat162 t;
    t.x = __float2bfloat16(a);
    t.y = __float2bfloat16(b);
    return *(u32*)&t;
}
__device__ inline float2 unpackbf2(u32 v) {
    union { u32 u; float f; } lo, hi;
    lo.u = v << 16;
    hi.u = v & 0xffff0000u;
    return make_float2(lo.f, hi.f);
}

// ---------------- small utility kernels ----------------
__global__ void k_zero_int(int* p, int n) {
    int i = blockIdx.x * blockDim.x + threadIdx.x;
    if (i < n) p[i] = 0;
}

__global__ void k_count(const int* __restrict__ ei, int* __restrict__ cnt, int e) {
    int i = blockIdx.x * blockDim.x + threadIdx.x;
    if (i < e) atomicAdd(&cnt[ei[e + i]], 1);   // dst rows live at ei[E..2E)
}

// ---------------- 3-phase parallel exclusive scan over cnt[n] ----------------
__global__ __launch_bounds__(256)
void k_scan_partial(const int* __restrict__ cnt, int* __restrict__ partial, int n) {
    __shared__ int s[256];
    const int t = threadIdx.x;
    const int base = blockIdx.x * 1024 + t * 4;
    int sum = 0;
#pragma unroll
    for (int i = 0; i < 4; i++) {
        int idx = base + i;
        if (idx < n) sum += cnt[idx];
    }
    s[t] = sum;
    __syncthreads();
#pragma unroll
    for (int off = 128; off > 0; off >>= 1) {
        if (t < off) s[t] += s[t + off];
        __syncthreads();
    }
    if (t == 0) partial[blockIdx.x] = s[0];
}

__global__ __launch_bounds__(256)
void k_scan_top(int* __restrict__ partial, int nb) {
    __shared__ int s[256];
    const int t = threadIdx.x;
    s[t] = (t < nb) ? partial[t] : 0;
    __syncthreads();
    for (int off = 1; off < 256; off <<= 1) {
        int v = (t >= off) ? s[t - off] : 0;
        __syncthreads();
        s[t] += v;
        __syncthreads();
    }
    if (t < nb) partial[t] = (t == 0) ? 0 : s[t - 1];
}

__global__ __launch_bounds__(256)
void k_scan_final(const int* __restrict__ cnt, const int* __restrict__ partial,
                  int* __restrict__ row_start, float* __restrict__ dis, int n) {
    __shared__ int s[256];
    const int t = threadIdx.x;
    const int base = blockIdx.x * 1024 + t * 4;
    int v[4];
    int sum = 0;
#pragma unroll
    for (int i = 0; i < 4; i++) {
        int idx = base + i;
        v[i] = (idx < n) ? cnt[idx] : 0;
        sum += v[i];
    }
    s[t] = sum;
    __syncthreads();
    for (int off = 1; off < 256; off <<= 1) {
        int x = (t >= off) ? s[t - off] : 0;
        __syncthreads();
        s[t] += x;
        __syncthreads();
    }
    int run = partial[blockIdx.x] + ((t == 0) ? 0 : s[t - 1]);
#pragma unroll
    for (int i = 0; i < 4; i++) {
        int idx = base + i;
        if (idx < n) {
            row_start[idx] = run;
            dis[idx] = rsqrtf((float)v[i] + 1.0f);
            run += v[i];
        }
    }
}

// ---------------- XCD-partitioned bucket fill ----------------
#define FILL_CHUNKS 256
__global__ __launch_bounds__(256)
void k_fill_part(const int* __restrict__ ei, const int* __restrict__ row_start,
                 int* __restrict__ cur, int* __restrict__ csr_src, int e, int n) {
    const int part = blockIdx.x & 7;
    const int psz  = (n + 7) >> 3;
    const int plo  = part * psz;
    const int phi  = min(n, plo + psz);
    const int per  = (e + FILL_CHUNKS - 1) / FILL_CHUNKS;
    const int i0 = (blockIdx.x >> 3) * per;
    const int i1 = min(e, i0 + per);
    for (int i = i0 + threadIdx.x; i < i1; i += 256) {
        int dst = ei[e + i];
        if (dst >= plo && dst < phi) {
            int src = ei[i];
            int pos = row_start[dst] + atomicAdd(&cur[dst], 1);
            csr_src[pos] = src;
        }
    }
}

// ------- GEMM: chunked-bf16 output: chunk c holds cols [16c,16c+16) -------
// hwc[c*N*8 + row*8 + w] (u32) = bf16 cols {16c+2w, 16c+2w+1} of row
#define BM 64
#define BK 32

__launch_bounds__(256, 2)
__global__ void k_gemm_scale_bf(const float* __restrict__ A,
                                const float* __restrict__ W,
                                const float* __restrict__ dis,
                                u32* __restrict__ outbf,
                                int n)
{
    __shared__ float sA[BK][BM + 4];
    __shared__ float sB[BK][128];
    const int tid = threadIdx.x;
    const int row0 = blockIdx.x * BM;
    const int tr = tid >> 4;
    const int tc = tid & 15;

    float acc[4][8];
#pragma unroll
    for (int r = 0; r < 4; r++)
#pragma unroll
        for (int c = 0; c < 8; c++) acc[r][c] = 0.f;

    for (int k0 = 0; k0 < 128; k0 += BK) {
        __syncthreads();
#pragma unroll
        for (int i = 0; i < 2; i++) {
            int f = tid + i * 256;
            int row = f >> 3;
            int kq = f & 7;
            int gr = row0 + row; if (gr >= n) gr = n - 1;
            float4 v = *(const float4*)&A[(long long)gr * 128 + k0 + kq * 4];
            sA[kq * 4 + 0][row] = v.x;
            sA[kq * 4 + 1][row] = v.y;
            sA[kq * 4 + 2][row] = v.z;
            sA[kq * 4 + 3][row] = v.w;
        }
#pragma unroll
        for (int i = 0; i < 4; i++) {
            int f = tid + i * 256;
            int kk = f >> 5;
            int cq = f & 31;
            *(float4*)&sB[kk][cq * 4] = *(const float4*)&W[(k0 + kk) * 128 + cq * 4];
        }
        __syncthreads();
#pragma unroll
        for (int kk = 0; kk < BK; kk++) {
            float4 a4 = *(const float4*)&sA[kk][tr * 4];
            float4 bl = *(const float4*)&sB[kk][tc * 4];
            float4 bh = *(const float4*)&sB[kk][64 + tc * 4];
            float a_[4] = {a4.x, a4.y, a4.z, a4.w};
            float b_[8] = {bl.x, bl.y, bl.z, bl.w, bh.x, bh.y, bh.z, bh.w};
#pragma unroll
            for (int r = 0; r < 4; r++)
#pragma unroll
                for (int c = 0; c < 8; c++)
                    acc[r][c] += a_[r] * b_[c];
        }
    }
    const int c0 = tc >> 2;            // chunk for lo cols (tc*4 .. tc*4+3)
    const int w0 = (tc & 3) * 2;       // u32 word within the 8-word row
#pragma unroll
    for (int r = 0; r < 4; r++) {
        int gr = row0 + tr * 4 + r;
        if (gr < n) {
            float d = dis[gr];
            uint2 lo, hi;
            lo.x = packbf2(acc[r][0] * d, acc[r][1] * d);
            lo.y = packbf2(acc[r][2] * d, acc[r][3] * d);
            hi.x = packbf2(acc[r][4] * d, acc[r][5] * d);
            hi.y = packbf2(acc[r][6] * d, acc[r][7] * d);
            *(uint2*)&outbf[(size_t)c0 * NN * 8 + (size_t)gr * 8 + w0]       = lo;
            *(uint2*)&outbf[(size_t)(c0 + 4) * NN * 8 + (size_t)gr * 8 + w0] = hi;
        }
    }
}

// ------- XCD-partitioned gather-aggregate over L2-resident 3.2MB chunk -------
// block b: partition p=b&7 (XCD-pinned chunk), nodes [(b>>3)*32, +32).
// wave handles one node; 8 edges in flight (lane = 8*edge_sub + col).
__launch_bounds__(256)
__global__ void k_agg_chunk(const int* __restrict__ csr_src,
                            const int* __restrict__ row_start,
                            const u32* __restrict__ hwc,
                            const float* __restrict__ dis,
                            const float* __restrict__ bias,
                            float* __restrict__ out, int n, int e)
{
    const int p    = blockIdx.x & 7;
    const int lane = threadIdx.x & 63;
    const int wv   = threadIdx.x >> 6;
    const int esub = lane >> 3;
    const int col  = lane & 7;
    const u32* __restrict__ chunk = hwc + (size_t)p * NN * 8;
    const int node0 = (blockIdx.x >> 3) * 32 + wv;

#pragma unroll
    for (int it = 0; it < 8; ++it) {
        const int node = node0 + it * 4;
        if (node >= n) continue;
        const int beg = row_start[node];
        const int end = (node == n - 1) ? e : row_start[node + 1];

        float2 acc = make_float2(0.f, 0.f);
        if (esub == 0) acc = unpackbf2(chunk[(size_t)node * 8 + col]);  // self-loop

        int i = beg + esub;
        for (; i + 8 < end; i += 16) {
            int s0 = csr_src[i];
            int s1 = csr_src[i + 8];
            float2 v0 = unpackbf2(chunk[(size_t)s0 * 8 + col]);
            float2 v1 = unpackbf2(chunk[(size_t)s1 * 8 + col]);
            acc.x += v0.x + v1.x;
            acc.y += v0.y + v1.y;
        }
        if (i < end) {
            float2 v0 = unpackbf2(chunk[(size_t)csr_src[i] * 8 + col]);
            acc.x += v0.x;
            acc.y += v0.y;
        }
        // reduce over the 8 edge_sub groups (lanes sharing `col`)
        acc.x += __shfl_xor(acc.x, 8);  acc.y += __shfl_xor(acc.y, 8);
        acc.x += __shfl_xor(acc.x, 16); acc.y += __shfl_xor(acc.y, 16);
        acc.x += __shfl_xor(acc.x, 32); acc.y += __shfl_xor(acc.y, 32);

        if (esub == 0) {
            float d = dis[node];
            float2 bb = *(const float2*)&bias[p * 16 + col * 2];
            float2 o;
            o.x = fmaxf(fmaf(d, acc.x, bb.x), 0.f);
            o.y = fmaxf(fmaf(d, acc.y, bb.y), 0.f);
            *(float2*)&out[(size_t)node * 128 + p * 16 + col * 2] = o;
        }
    }
}

// ---------------- FC head ----------------
__launch_bounds__(256)
__global__ void k_fc(const float* __restrict__ h,
                     const float* __restrict__ Wfc,
                     const float* __restrict__ bfc,
                     float* __restrict__ out, int n)
{
    __shared__ float sW[128 * 8];
    __shared__ float sH[32][132];
    const int tid = threadIdx.x;
    *(float4*)&sW[tid * 4] = *(const float4*)&Wfc[tid * 4];
    const int n0 = blockIdx.x * 32;
#pragma unroll
    for (int i = 0; i < 4; i++) {
        int f = tid + i * 256;
        int node = f >> 5;
        int kq = f & 31;
        int gn = n0 + node; if (gn >= n) gn = n - 1;
        *(float4*)&sH[node][kq * 4] = *(const float4*)&h[(long long)gn * 128 + kq * 4];
    }
    __syncthreads();
    const int node = tid >> 3;
    const int a = tid & 7;
    float acc = bfc[a];
#pragma unroll
    for (int k = 0; k < 128; k++)
        acc += sH[node][k] * sW[k * 8 + a];
    int gn = n0 + node;
    if (gn < n) out[gn * 8 + a] = acc;
}

extern "C" void kernel_launch(void* const* d_in, const int* in_sizes, int n_in,
                              void* d_out, int out_size, void* d_ws, size_t ws_size,
                              hipStream_t stream) {
    const float* x   = (const float*)d_in[0];
    const int*   ei  = (const int*)d_in[1];
    const float* W1  = (const float*)d_in[2];
    const float* b1  = (const float*)d_in[3];
    const float* W2  = (const float*)d_in[4];
    const float* b2  = (const float*)d_in[5];
    const float* Wfc = (const float*)d_in[6];
    const float* bfc = (const float*)d_in[7];
    float* out = (float*)d_out;

    const int n = NN, e = EE;
    const int nb = (n + 1023) / 1024;

    // workspace layout
    char* ws = (char*)d_ws;
    float* dis       = (float*)(ws);                        // N f32
    int*   cnt       = (int*)  (ws + (1 << 19));            // N i32
    int*   row_start = (int*)  (ws + 2 * (1 << 19));        // N i32
    int*   cur       = (int*)  (ws + 3 * (1 << 19));        // N i32
    int*   partial   = (int*)  (ws + 4 * (1 << 19));        // nb i32
    int*   csr_src   = (int*)  (ws + 4 * (1 << 19) + 4096); // E i32 (6.4 MB)
    char*  big       = ws + 4 * (1 << 19) + 4096 + ((size_t)EE * 4 + 4096);
    u32*   hwbf      = (u32*)(big);                          // N*64 u32 (25.6 MB, chunked)
    float* bufH      = (float*)(big + (size_t)NN * 64 * 4);  // N*128 f32 (51.2 MB)

    const int g256n = (n + 255) / 256;
    const int g256e = (e + 255) / 256;

    // ---- CSR build + norms ----
    k_zero_int<<<g256n, 256, 0, stream>>>(cnt, n);
    k_count<<<g256e, 256, 0, stream>>>(ei, cnt, e);
    k_scan_partial<<<nb, 256, 0, stream>>>(cnt, partial, n);
    k_scan_top<<<1, 256, 0, stream>>>(partial, nb);
    k_scan_final<<<nb, 256, 0, stream>>>(cnt, partial, row_start, dis, n);
    k_zero_int<<<g256n, 256, 0, stream>>>(cur, n);
    k_fill_part<<<FILL_CHUNKS * 8, 256, 0, stream>>>(ei, row_start, cur, csr_src, e, n);

    const int gemm_grid = (n + BM - 1) / BM;
    const int agg_grid  = 8 * ((n + 31) / 32);   // 8 partitions x node-blocks of 32

    // ---- layer 1 ----
    k_gemm_scale_bf<<<gemm_grid, 256, 0, stream>>>(x, W1, dis, hwbf, n);
    k_agg_chunk<<<agg_grid, 256, 0, stream>>>(csr_src, row_start, hwbf, dis, b1, bufH, n, e);

    // ---- layer 2 ----
    k_gemm_scale_bf<<<gemm_grid, 256, 0, stream>>>(bufH, W2, dis, hwbf, n);
    k_agg_chunk<<<agg_grid, 256, 0, stream>>>(csr_src, row_start, hwbf, dis, b2, bufH, n, e);

    // ---- FC head ----
    k_fc<<<(n + 31) / 32, 256, 0, stream>>>(bufH, Wfc, bfc, out, n);
}

// Round 6
// 404.475 us; speedup vs baseline: 1.6369x; 1.6369x over previous
//
#include <hip/hip_runtime.h>
#include <hip/hip_bf16.h>

#define NN 100000
#define EE 1600000
#define FF 128
#define HH 128
#define AA 8

typedef unsigned int u32;

__device__ inline u32 packbf2(float a, float b) {
    __hip_bfloat162 t;
    t.x = __float2bfloat16(a);
    t.y = __float2bfloat16(b);
    return *(u32*)&t;
}
__device__ inline float2 unpackbf2(u32 v) {
    union { u32 u; float f; } lo, hi;
    lo.u = v << 16;
    hi.u = v & 0xffff0000u;
    return make_float2(lo.f, hi.f);
}

// ---------------- small utility kernels ----------------
__global__ void k_zero_int(int* p, int n) {
    int i = blockIdx.x * blockDim.x + threadIdx.x;
    if (i < n) p[i] = 0;
}

__global__ void k_count(const int* __restrict__ ei, int* __restrict__ cnt, int e) {
    int i = blockIdx.x * blockDim.x + threadIdx.x;
    if (i < e) atomicAdd(&cnt[ei[e + i]], 1);   // dst rows live at ei[E..2E)
}

// ---------------- 3-phase parallel exclusive scan over cnt[n] ----------------
__global__ __launch_bounds__(256)
void k_scan_partial(const int* __restrict__ cnt, int* __restrict__ partial, int n) {
    __shared__ int s[256];
    const int t = threadIdx.x;
    const int base = blockIdx.x * 1024 + t * 4;
    int sum = 0;
#pragma unroll
    for (int i = 0; i < 4; i++) {
        int idx = base + i;
        if (idx < n) sum += cnt[idx];
    }
    s[t] = sum;
    __syncthreads();
#pragma unroll
    for (int off = 128; off > 0; off >>= 1) {
        if (t < off) s[t] += s[t + off];
        __syncthreads();
    }
    if (t == 0) partial[blockIdx.x] = s[0];
}

__global__ __launch_bounds__(256)
void k_scan_top(int* __restrict__ partial, int nb) {
    __shared__ int s[256];
    const int t = threadIdx.x;
    s[t] = (t < nb) ? partial[t] : 0;
    __syncthreads();
    for (int off = 1; off < 256; off <<= 1) {
        int v = (t >= off) ? s[t - off] : 0;
        __syncthreads();
        s[t] += v;
        __syncthreads();
    }
    if (t < nb) partial[t] = (t == 0) ? 0 : s[t - 1];
}

__global__ __launch_bounds__(256)
void k_scan_final(const int* __restrict__ cnt, const int* __restrict__ partial,
                  int* __restrict__ row_start, float* __restrict__ dis, int n) {
    __shared__ int s[256];
    const int t = threadIdx.x;
    const int base = blockIdx.x * 1024 + t * 4;
    int v[4];
    int sum = 0;
#pragma unroll
    for (int i = 0; i < 4; i++) {
        int idx = base + i;
        v[i] = (idx < n) ? cnt[idx] : 0;
        sum += v[i];
    }
    s[t] = sum;
    __syncthreads();
    for (int off = 1; off < 256; off <<= 1) {
        int x = (t >= off) ? s[t - off] : 0;
        __syncthreads();
        s[t] += x;
        __syncthreads();
    }
    int run = partial[blockIdx.x] + ((t == 0) ? 0 : s[t - 1]);
#pragma unroll
    for (int i = 0; i < 4; i++) {
        int idx = base + i;
        if (idx < n) {
            row_start[idx] = run;
            dis[idx] = rsqrtf((float)v[i] + 1.0f);
            run += v[i];
        }
    }
}

// ---------------- XCD-partitioned bucket fill ----------------
#define FILL_CHUNKS 256
__global__ __launch_bounds__(256)
void k_fill_part(const int* __restrict__ ei, const int* __restrict__ row_start,
                 int* __restrict__ cur, int* __restrict__ csr_src, int e, int n) {
    const int part = blockIdx.x & 7;
    const int psz  = (n + 7) >> 3;
    const int plo  = part * psz;
    const int phi  = min(n, plo + psz);
    const int per  = (e + FILL_CHUNKS - 1) / FILL_CHUNKS;
    const int i0 = (blockIdx.x >> 3) * per;
    const int i1 = min(e, i0 + per);
    for (int i = i0 + threadIdx.x; i < i1; i += 256) {
        int dst = ei[e + i];
        if (dst >= plo && dst < phi) {
            int src = ei[i];
            int pos = row_start[dst] + atomicAdd(&cur[dst], 1);
            csr_src[pos] = src;
        }
    }
}

// ------- GEMM (f32 A input): hwbf[i] = bf16( dis[i] * (A[i] @ W) ), rows of 64 u32 -------
#define BM 64
#define BK 32

__launch_bounds__(256, 2)
__global__ void k_gemm_f32in(const float* __restrict__ A,
                             const float* __restrict__ W,
                             const float* __restrict__ dis,
                             u32* __restrict__ outbf, int n)
{
    __shared__ float sA[BK][BM + 4];
    __shared__ float sB[BK][128];
    const int tid = threadIdx.x;
    const int row0 = blockIdx.x * BM;
    const int tr = tid >> 4;
    const int tc = tid & 15;

    float acc[4][8];
#pragma unroll
    for (int r = 0; r < 4; r++)
#pragma unroll
        for (int c = 0; c < 8; c++) acc[r][c] = 0.f;

    for (int k0 = 0; k0 < 128; k0 += BK) {
        __syncthreads();
#pragma unroll
        for (int i = 0; i < 2; i++) {
            int f = tid + i * 256;
            int row = f >> 3;
            int kq = f & 7;
            int gr = row0 + row; if (gr >= n) gr = n - 1;
            float4 v = *(const float4*)&A[(long long)gr * 128 + k0 + kq * 4];
            sA[kq * 4 + 0][row] = v.x;
            sA[kq * 4 + 1][row] = v.y;
            sA[kq * 4 + 2][row] = v.z;
            sA[kq * 4 + 3][row] = v.w;
        }
#pragma unroll
        for (int i = 0; i < 4; i++) {
            int f = tid + i * 256;
            int kk = f >> 5;
            int cq = f & 31;
            *(float4*)&sB[kk][cq * 4] = *(const float4*)&W[(k0 + kk) * 128 + cq * 4];
        }
        __syncthreads();
#pragma unroll
        for (int kk = 0; kk < BK; kk++) {
            float4 a4 = *(const float4*)&sA[kk][tr * 4];
            float4 bl = *(const float4*)&sB[kk][tc * 4];
            float4 bh = *(const float4*)&sB[kk][64 + tc * 4];
            float a_[4] = {a4.x, a4.y, a4.z, a4.w};
            float b_[8] = {bl.x, bl.y, bl.z, bl.w, bh.x, bh.y, bh.z, bh.w};
#pragma unroll
            for (int r = 0; r < 4; r++)
#pragma unroll
                for (int c = 0; c < 8; c++)
                    acc[r][c] += a_[r] * b_[c];
        }
    }
#pragma unroll
    for (int r = 0; r < 4; r++) {
        int gr = row0 + tr * 4 + r;
        if (gr < n) {
            float d = dis[gr];
            uint2 lo, hi;
            lo.x = packbf2(acc[r][0] * d, acc[r][1] * d);
            lo.y = packbf2(acc[r][2] * d, acc[r][3] * d);
            hi.x = packbf2(acc[r][4] * d, acc[r][5] * d);
            hi.y = packbf2(acc[r][6] * d, acc[r][7] * d);
            *(uint2*)&outbf[(long long)gr * 64 + tc * 2]      = lo;
            *(uint2*)&outbf[(long long)gr * 64 + 32 + tc * 2] = hi;
        }
    }
}

// ------- GEMM (bf16-packed A input), same output -------
__launch_bounds__(256, 2)
__global__ void k_gemm_bf16in(const u32* __restrict__ Abf,   // rows of 64 u32
                              const float* __restrict__ W,
                              const float* __restrict__ dis,
                              u32* __restrict__ outbf, int n)
{
    __shared__ float sA[BK][BM + 4];
    __shared__ float sB[BK][128];
    const int tid = threadIdx.x;
    const int row0 = blockIdx.x * BM;
    const int tr = tid >> 4;
    const int tc = tid & 15;

    float acc[4][8];
#pragma unroll
    for (int r = 0; r < 4; r++)
#pragma unroll
        for (int c = 0; c < 8; c++) acc[r][c] = 0.f;

    for (int k0 = 0; k0 < 128; k0 += BK) {
        __syncthreads();
        // stage A tile: 64 rows x 32 k = 64 x 16 u32 -> 512 uint2
#pragma unroll
        for (int i = 0; i < 2; i++) {
            int f = tid + i * 256;       // uint2 id
            int row = f >> 3;            // 0..63
            int wq = f & 7;              // 0..7
            int gr = row0 + row; if (gr >= n) gr = n - 1;
            uint2 v = *(const uint2*)&Abf[(long long)gr * 64 + (k0 >> 1) + wq * 2];
            float2 p0 = unpackbf2(v.x);
            float2 p1 = unpackbf2(v.y);
            sA[wq * 4 + 0][row] = p0.x;
            sA[wq * 4 + 1][row] = p0.y;
            sA[wq * 4 + 2][row] = p1.x;
            sA[wq * 4 + 3][row] = p1.y;
        }
#pragma unroll
        for (int i = 0; i < 4; i++) {
            int f = tid + i * 256;
            int kk = f >> 5;
            int cq = f & 31;
            *(float4*)&sB[kk][cq * 4] = *(const float4*)&W[(k0 + kk) * 128 + cq * 4];
        }
        __syncthreads();
#pragma unroll
        for (int kk = 0; kk < BK; kk++) {
            float4 a4 = *(const float4*)&sA[kk][tr * 4];
            float4 bl = *(const float4*)&sB[kk][tc * 4];
            float4 bh = *(const float4*)&sB[kk][64 + tc * 4];
            float a_[4] = {a4.x, a4.y, a4.z, a4.w};
            float b_[8] = {bl.x, bl.y, bl.z, bl.w, bh.x, bh.y, bh.z, bh.w};
#pragma unroll
            for (int r = 0; r < 4; r++)
#pragma unroll
                for (int c = 0; c < 8; c++)
                    acc[r][c] += a_[r] * b_[c];
        }
    }
#pragma unroll
    for (int r = 0; r < 4; r++) {
        int gr = row0 + tr * 4 + r;
        if (gr < n) {
            float d = dis[gr];
            uint2 lo, hi;
            lo.x = packbf2(acc[r][0] * d, acc[r][1] * d);
            lo.y = packbf2(acc[r][2] * d, acc[r][3] * d);
            hi.x = packbf2(acc[r][4] * d, acc[r][5] * d);
            hi.y = packbf2(acc[r][6] * d, acc[r][7] * d);
            *(uint2*)&outbf[(long long)gr * 64 + tc * 2]      = lo;
            *(uint2*)&outbf[(long long)gr * 64 + 32 + tc * 2] = hi;
        }
    }
}

// ------- gather-aggregate (8-way MLP) + self + scale + bias + relu -> bf16 ------
// one 64-lane wave per dst node; lane owns 2 feature columns (1 u32 = 2 bf16)
__launch_bounds__(256)
__global__ void k_agg(const int* __restrict__ csr_src,
                      const int* __restrict__ row_start,
                      const u32* __restrict__ hw,      // bf16x2 rows of 64
                      const float* __restrict__ dis,
                      const float* __restrict__ b,
                      u32* __restrict__ out, int n, int e)
{
    int node = blockIdx.x * 4 + (threadIdx.x >> 6);
    if (node >= n) return;
    int lane = threadIdx.x & 63;
    int beg = row_start[node];
    int end = (node == n - 1) ? e : row_start[node + 1];

    float2 acc = unpackbf2(hw[(long long)node * 64 + lane]);  // self-loop term
    int i = beg;
    // 8-way unrolled: 8 independent csr reads, then 8 independent gathers
    for (; i + 7 < end; i += 8) {
        int s0 = csr_src[i];
        int s1 = csr_src[i + 1];
        int s2 = csr_src[i + 2];
        int s3 = csr_src[i + 3];
        int s4 = csr_src[i + 4];
        int s5 = csr_src[i + 5];
        int s6 = csr_src[i + 6];
        int s7 = csr_src[i + 7];
        u32 a0 = hw[(long long)s0 * 64 + lane];
        u32 a1 = hw[(long long)s1 * 64 + lane];
        u32 a2 = hw[(long long)s2 * 64 + lane];
        u32 a3 = hw[(long long)s3 * 64 + lane];
        u32 a4 = hw[(long long)s4 * 64 + lane];
        u32 a5 = hw[(long long)s5 * 64 + lane];
        u32 a6 = hw[(long long)s6 * 64 + lane];
        u32 a7 = hw[(long long)s7 * 64 + lane];
        float2 v0 = unpackbf2(a0), v1 = unpackbf2(a1), v2 = unpackbf2(a2), v3 = unpackbf2(a3);
        float2 v4 = unpackbf2(a4), v5 = unpackbf2(a5), v6 = unpackbf2(a6), v7 = unpackbf2(a7);
        acc.x += ((v0.x + v1.x) + (v2.x + v3.x)) + ((v4.x + v5.x) + (v6.x + v7.x));
        acc.y += ((v0.y + v1.y) + (v2.y + v3.y)) + ((v4.y + v5.y) + (v6.y + v7.y));
    }
    for (; i + 1 < end; i += 2) {
        int s0 = csr_src[i];
        int s1 = csr_src[i + 1];
        float2 v0 = unpackbf2(hw[(long long)s0 * 64 + lane]);
        float2 v1 = unpackbf2(hw[(long long)s1 * 64 + lane]);
        acc.x += v0.x + v1.x;
        acc.y += v0.y + v1.y;
    }
    if (i < end) {
        float2 v0 = unpackbf2(hw[(long long)csr_src[i] * 64 + lane]);
        acc.x += v0.x;
        acc.y += v0.y;
    }
    float d = dis[node];
    float2 bb = *(const float2*)&b[lane * 2];
    float ox = fmaxf(fmaf(d, acc.x, bb.x), 0.f);
    float oy = fmaxf(fmaf(d, acc.y, bb.y), 0.f);
    out[(long long)node * 64 + lane] = packbf2(ox, oy);
}

// ---------------- FC head (bf16-packed input) ----------------
__launch_bounds__(256)
__global__ void k_fc(const u32* __restrict__ hbf,   // rows of 64 u32
                     const float* __restrict__ Wfc,
                     const float* __restrict__ bfc,
                     float* __restrict__ out, int n)
{
    __shared__ float sW[128 * 8];
    __shared__ float sH[32][132];
    const int tid = threadIdx.x;
    *(float4*)&sW[tid * 4] = *(const float4*)&Wfc[tid * 4];
    const int n0 = blockIdx.x * 32;
#pragma unroll
    for (int i = 0; i < 4; i++) {
        int f = tid + i * 256;     // uint2 id in [0,1024)
        int node = f >> 5;         // 0..31
        int wq = f & 31;           // 0..31 -> words wq*2, wq*2+1 -> cols wq*4..+3
        int gn = n0 + node; if (gn >= n) gn = n - 1;
        uint2 v = *(const uint2*)&hbf[(long long)gn * 64 + wq * 2];
        float2 p0 = unpackbf2(v.x);
        float2 p1 = unpackbf2(v.y);
        sH[node][wq * 4 + 0] = p0.x;
        sH[node][wq * 4 + 1] = p0.y;
        sH[node][wq * 4 + 2] = p1.x;
        sH[node][wq * 4 + 3] = p1.y;
    }
    __syncthreads();
    const int node = tid >> 3;
    const int a = tid & 7;
    float acc = bfc[a];
#pragma unroll
    for (int k = 0; k < 128; k++)
        acc += sH[node][k] * sW[k * 8 + a];
    int gn = n0 + node;
    if (gn < n) out[gn * 8 + a] = acc;
}

extern "C" void kernel_launch(void* const* d_in, const int* in_sizes, int n_in,
                              void* d_out, int out_size, void* d_ws, size_t ws_size,
                              hipStream_t stream) {
    const float* x   = (const float*)d_in[0];
    const int*   ei  = (const int*)d_in[1];
    const float* W1  = (const float*)d_in[2];
    const float* b1  = (const float*)d_in[3];
    const float* W2  = (const float*)d_in[4];
    const float* b2  = (const float*)d_in[5];
    const float* Wfc = (const float*)d_in[6];
    const float* bfc = (const float*)d_in[7];
    float* out = (float*)d_out;

    const int n = NN, e = EE;
    const int nb = (n + 1023) / 1024;

    // workspace layout
    char* ws = (char*)d_ws;
    float* dis       = (float*)(ws);                        // N f32
    int*   cnt       = (int*)  (ws + (1 << 19));            // N i32
    int*   row_start = (int*)  (ws + 2 * (1 << 19));        // N i32
    int*   cur       = (int*)  (ws + 3 * (1 << 19));        // N i32
    int*   partial   = (int*)  (ws + 4 * (1 << 19));        // nb i32
    int*   csr_src   = (int*)  (ws + 4 * (1 << 19) + 4096); // E i32 (6.4 MB)
    char*  big       = ws + 4 * (1 << 19) + 4096 + ((size_t)EE * 4 + 4096);
    u32*   hwbf      = (u32*)(big);                          // N*64 u32 (25.6 MB)
    u32*   hbf       = (u32*)(big + (size_t)NN * 64 * 4);    // N*64 u32 (25.6 MB)

    const int g256n = (n + 255) / 256;
    const int g256e = (e + 255) / 256;

    // ---- CSR build + norms ----
    k_zero_int<<<g256n, 256, 0, stream>>>(cnt, n);
    k_count<<<g256e, 256, 0, stream>>>(ei, cnt, e);
    k_scan_partial<<<nb, 256, 0, stream>>>(cnt, partial, n);
    k_scan_top<<<1, 256, 0, stream>>>(partial, nb);
    k_scan_final<<<nb, 256, 0, stream>>>(cnt, partial, row_start, dis, n);
    k_zero_int<<<g256n, 256, 0, stream>>>(cur, n);
    k_fill_part<<<FILL_CHUNKS * 8, 256, 0, stream>>>(ei, row_start, cur, csr_src, e, n);

    const int gemm_grid = (n + BM - 1) / BM;
    const int agg_grid  = (n + 3) / 4;

    // ---- layer 1 ----
    k_gemm_f32in<<<gemm_grid, 256, 0, stream>>>(x, W1, dis, hwbf, n);
    k_agg<<<agg_grid, 256, 0, stream>>>(csr_src, row_start, hwbf, dis, b1, hbf, n, e);

    // ---- layer 2 ----
    k_gemm_bf16in<<<gemm_grid, 256, 0, stream>>>(hbf, W2, dis, hwbf, n);
    k_agg<<<agg_grid, 256, 0, stream>>>(csr_src, row_start, hwbf, dis, b2, hbf, n, e);

    // ---- FC head ----
    k_fc<<<(n + 31) / 32, 256, 0, stream>>>(hbf, Wfc, bfc, out, n);
}

// Round 7
// 349.075 us; speedup vs baseline: 1.8966x; 1.1587x over previous
//
#include <hip/hip_runtime.h>
#include <hip/hip_bf16.h>

#define NN 100000
#define EE 1600000
#define FF 128
#define HH 128
#define AA 8

#define PSZ 12500        // nodes per XCD partition (NN/8)
#define BINCAP 240000    // slab capacity per partition (E/8 = 200k avg)

typedef unsigned int u32;
typedef unsigned short ushort_t;

using bf16x8 = __attribute__((ext_vector_type(8))) short;
using f32x4  = __attribute__((ext_vector_type(4))) float;

__device__ inline u32 packbf2(float a, float b) {
    __hip_bfloat162 t;
    t.x = __float2bfloat16(a);
    t.y = __float2bfloat16(b);
    return *(u32*)&t;
}
__device__ inline float2 unpackbf2(u32 v) {
    union { u32 u; float f; } lo, hi;
    lo.u = v << 16;
    hi.u = v & 0xffff0000u;
    return make_float2(lo.f, hi.f);
}

// ---------------- init: zero cnt, cur, bin counters ----------------
__global__ void k_init(int* cnt, int* cur, int* bincnt, int n) {
    int i = blockIdx.x * blockDim.x + threadIdx.x;
    if (i < n) { cnt[i] = 0; cur[i] = 0; }
    if (i < 8) bincnt[i] = 0;
}

// ---------------- W transpose: W f32 [128][128] -> WT bf16 u32 [n=128][k-words=64] ----
__global__ __launch_bounds__(256)
void k_wt(const float* __restrict__ W, u32* __restrict__ WT) {
    __shared__ float tile[32][33];
    const int tk = (blockIdx.x >> 2) * 32;
    const int tn = (blockIdx.x & 3) * 32;
    const int t = threadIdx.x;
    {
        int r = t >> 3, c4 = t & 7;
        float4 v = *(const float4*)&W[(tk + r) * 128 + tn + c4 * 4];
        tile[r][c4 * 4 + 0] = v.x;
        tile[r][c4 * 4 + 1] = v.y;
        tile[r][c4 * 4 + 2] = v.z;
        tile[r][c4 * 4 + 3] = v.w;
    }
    __syncthreads();
    {
        int nl = t >> 3, w = t & 7;   // 2 u32 words per thread (4 k each)
        u32 w0 = packbf2(tile[w * 4 + 0][nl], tile[w * 4 + 1][nl]);
        u32 w1 = packbf2(tile[w * 4 + 2][nl], tile[w * 4 + 3][nl]);
        *(uint2*)&WT[(size_t)(tn + nl) * 64 + (tk >> 1) + w * 2] = make_uint2(w0, w1);
    }
}

// ---------------- bin edges into 8 dst-partition slabs + fused degree count ----
__global__ __launch_bounds__(256)
void k_bin(const int* __restrict__ ei, int* __restrict__ g_bincnt,
           int2* __restrict__ binbuf, int* __restrict__ cnt, int e) {
    __shared__ int cnt_l[8], base_l[8], cur_l[8];
    const int t = threadIdx.x;
    if (t < 8) cnt_l[t] = 0;
    __syncthreads();
    const int per = (e + gridDim.x - 1) / gridDim.x;
    const int i0 = blockIdx.x * per;
    const int i1 = min(e, i0 + per);
    // pass 1: local histogram
    for (int i = i0 + t; i < i1; i += 256) {
        int dst = ei[e + i];
        atomicAdd(&cnt_l[dst / PSZ], 1);
    }
    __syncthreads();
    if (t < 8) { base_l[t] = atomicAdd(&g_bincnt[t], cnt_l[t]); cur_l[t] = 0; }
    __syncthreads();
    // pass 2: emit packed (src,dst) + degree count
    for (int i = i0 + t; i < i1; i += 256) {
        int dst = ei[e + i];
        int src = ei[i];
        int p = dst / PSZ;
        int pos = base_l[p] + atomicAdd(&cur_l[p], 1);
        if (pos < BINCAP) binbuf[(size_t)p * BINCAP + pos] = make_int2(src, dst);
        atomicAdd(&cnt[dst], 1);
    }
}

// ---------------- 3-phase parallel exclusive scan over cnt[n] ----------------
__global__ __launch_bounds__(256)
void k_scan_partial(const int* __restrict__ cnt, int* __restrict__ partial, int n) {
    __shared__ int s[256];
    const int t = threadIdx.x;
    const int base = blockIdx.x * 1024 + t * 4;
    int sum = 0;
#pragma unroll
    for (int i = 0; i < 4; i++) {
        int idx = base + i;
        if (idx < n) sum += cnt[idx];
    }
    s[t] = sum;
    __syncthreads();
#pragma unroll
    for (int off = 128; off > 0; off >>= 1) {
        if (t < off) s[t] += s[t + off];
        __syncthreads();
    }
    if (t == 0) partial[blockIdx.x] = s[0];
}

__global__ __launch_bounds__(256)
void k_scan_top(int* __restrict__ partial, int nb) {
    __shared__ int s[256];
    const int t = threadIdx.x;
    s[t] = (t < nb) ? partial[t] : 0;
    __syncthreads();
    for (int off = 1; off < 256; off <<= 1) {
        int v = (t >= off) ? s[t - off] : 0;
        __syncthreads();
        s[t] += v;
        __syncthreads();
    }
    if (t < nb) partial[t] = (t == 0) ? 0 : s[t - 1];
}

__global__ __launch_bounds__(256)
void k_scan_final(const int* __restrict__ cnt, const int* __restrict__ partial,
                  int* __restrict__ row_start, float* __restrict__ dis, int n) {
    __shared__ int s[256];
    const int t = threadIdx.x;
    const int base = blockIdx.x * 1024 + t * 4;
    int v[4];
    int sum = 0;
#pragma unroll
    for (int i = 0; i < 4; i++) {
        int idx = base + i;
        v[i] = (idx < n) ? cnt[idx] : 0;
        sum += v[i];
    }
    s[t] = sum;
    __syncthreads();
    for (int off = 1; off < 256; off <<= 1) {
        int x = (t >= off) ? s[t - off] : 0;
        __syncthreads();
        s[t] += x;
        __syncthreads();
    }
    int run = partial[blockIdx.x] + ((t == 0) ? 0 : s[t - 1]);
#pragma unroll
    for (int i = 0; i < 4; i++) {
        int idx = base + i;
        if (idx < n) {
            row_start[idx] = run;
            dis[idx] = rsqrtf((float)v[i] + 1.0f);
            run += v[i];
        }
    }
}

// ---------------- XCD-pinned scatter from slab p into CSR slice p ----------------
__global__ __launch_bounds__(256)
void k_scatter_bin(const int2* __restrict__ binbuf, const int* __restrict__ g_bincnt,
                   const int* __restrict__ row_start, int* __restrict__ cur,
                   int* __restrict__ csr_src) {
    const int p  = blockIdx.x & 7;
    const int nb = gridDim.x >> 3;
    const int bi = blockIdx.x >> 3;
    const int c  = min(g_bincnt[p], BINCAP);
    const int per = (c + nb - 1) / nb;
    const int i0 = bi * per, i1 = min(c, i0 + per);
    for (int i = i0 + threadIdx.x; i < i1; i += 256) {
        int2 sd = binbuf[(size_t)p * BINCAP + i];
        int pos = row_start[sd.y] + atomicAdd(&cur[sd.y], 1);
        csr_src[pos] = sd.x;
    }
}

// ---------------- MFMA GEMM: outbf[i] = bf16(dis[i] * (A[i] @ W)) ----------------
// A: [n,128] (f32 or bf16-packed), WT: bf16 u32 [n=128][k-words=64]
#define LDK 136   // padded k stride (ushorts); row stride 272 B -> 2-way-free banks

template<int AF32>
__global__ __launch_bounds__(256)
void k_gemm_mfma(const void* __restrict__ Ain, const u32* __restrict__ WT,
                 const float* __restrict__ dis, u32* __restrict__ outbf, int n)
{
    __shared__ ushort_t sA[64 * LDK];
    __shared__ ushort_t sB[128 * LDK];
    const int tid = threadIdx.x;
    const int row0 = blockIdx.x * 64;

    // ---- stage A (64 rows x 128 k, bf16) ----
    if (AF32) {
        const float* A = (const float*)Ain;
#pragma unroll
        for (int i = 0; i < 8; i++) {
            int f = tid + i * 256;           // float4 id: 64 x 32
            int r = f >> 5, c4 = f & 31;
            int gr = row0 + r; if (gr >= n) gr = n - 1;
            float4 v = *(const float4*)&A[(size_t)gr * 128 + c4 * 4];
            *(uint2*)&sA[r * LDK + c4 * 4] =
                make_uint2(packbf2(v.x, v.y), packbf2(v.z, v.w));
        }
    } else {
        const u32* A = (const u32*)Ain;
#pragma unroll
        for (int i = 0; i < 4; i++) {
            int f = tid + i * 256;           // uint4 id: 64 x 16
            int r = f >> 4, q = f & 15;
            int gr = row0 + r; if (gr >= n) gr = n - 1;
            uint4 v = *(const uint4*)&A[(size_t)gr * 64 + q * 4];
            *(uint4*)&sA[r * LDK + q * 8] = v;
        }
    }
    // ---- stage B: WT (128 n-rows x 128 k) ----
#pragma unroll
    for (int i = 0; i < 8; i++) {
        int f = tid + i * 256;               // uint4 id: 128 x 16
        int r = f >> 4, q = f & 15;
        uint4 v = *(const uint4*)&WT[(size_t)r * 64 + q * 4];
        *(uint4*)&sB[r * LDK + q * 8] = v;
    }
    __syncthreads();

    const int l   = tid & 63;
    const int w   = tid >> 6;     // wave id: rows w*16..w*16+15
    const int col = l & 15;
    const int g   = l >> 4;       // k-group
    const ushort_t* pa = &sA[(w * 16 + col) * LDK + g * 8];
    const ushort_t* pb = &sB[col * LDK + g * 8];

    f32x4 acc[8] = {};
#pragma unroll
    for (int ks = 0; ks < 4; ks++) {
        bf16x8 a = *(const bf16x8*)(pa + ks * 32);
#pragma unroll
        for (int cf = 0; cf < 8; cf++) {
            bf16x8 b = *(const bf16x8*)(pb + (size_t)cf * 16 * LDK + ks * 32);
            acc[cf] = __builtin_amdgcn_mfma_f32_16x16x32_bf16(a, b, acc[cf], 0, 0, 0);
        }
    }

    // ---- epilogue: scale by dis[row], pack 2 cols -> u32, store ----
    const int grow0 = row0 + w * 16 + g * 4;
    float dvr[4];
#pragma unroll
    for (int r = 0; r < 4; r++)
        dvr[r] = (grow0 + r < n) ? dis[grow0 + r] : 0.f;
#pragma unroll
    for (int cf = 0; cf < 8; cf++) {
#pragma unroll
        for (int r = 0; r < 4; r++) {
            float val = acc[cf][r] * dvr[r];
            float oth = __shfl_xor(val, 1);
            if (!(l & 1) && (grow0 + r < n))
                outbf[(size_t)(grow0 + r) * 64 + (cf * 16 + col) / 2] = packbf2(val, oth);
        }
    }
}

// ------- gather-aggregate (8-way MLP) + self + scale + bias + relu -> bf16 ------
__launch_bounds__(256)
__global__ void k_agg(const int* __restrict__ csr_src,
                      const int* __restrict__ row_start,
                      const u32* __restrict__ hw,
                      const float* __restrict__ dis,
                      const float* __restrict__ b,
                      u32* __restrict__ out, int n, int e)
{
    int node = blockIdx.x * 4 + (threadIdx.x >> 6);
    if (node >= n) return;
    int lane = threadIdx.x & 63;
    int beg = row_start[node];
    int end = (node == n - 1) ? e : row_start[node + 1];

    float2 acc = unpackbf2(hw[(long long)node * 64 + lane]);  // self-loop
    int i = beg;
    for (; i + 7 < end; i += 8) {
        int s0 = csr_src[i];
        int s1 = csr_src[i + 1];
        int s2 = csr_src[i + 2];
        int s3 = csr_src[i + 3];
        int s4 = csr_src[i + 4];
        int s5 = csr_src[i + 5];
        int s6 = csr_src[i + 6];
        int s7 = csr_src[i + 7];
        u32 a0 = hw[(long long)s0 * 64 + lane];
        u32 a1 = hw[(long long)s1 * 64 + lane];
        u32 a2 = hw[(long long)s2 * 64 + lane];
        u32 a3 = hw[(long long)s3 * 64 + lane];
        u32 a4 = hw[(long long)s4 * 64 + lane];
        u32 a5 = hw[(long long)s5 * 64 + lane];
        u32 a6 = hw[(long long)s6 * 64 + lane];
        u32 a7 = hw[(long long)s7 * 64 + lane];
        float2 v0 = unpackbf2(a0), v1 = unpackbf2(a1), v2 = unpackbf2(a2), v3 = unpackbf2(a3);
        float2 v4 = unpackbf2(a4), v5 = unpackbf2(a5), v6 = unpackbf2(a6), v7 = unpackbf2(a7);
        acc.x += ((v0.x + v1.x) + (v2.x + v3.x)) + ((v4.x + v5.x) + (v6.x + v7.x));
        acc.y += ((v0.y + v1.y) + (v2.y + v3.y)) + ((v4.y + v5.y) + (v6.y + v7.y));
    }
    for (; i + 1 < end; i += 2) {
        int s0 = csr_src[i];
        int s1 = csr_src[i + 1];
        float2 v0 = unpackbf2(hw[(long long)s0 * 64 + lane]);
        float2 v1 = unpackbf2(hw[(long long)s1 * 64 + lane]);
        acc.x += v0.x + v1.x;
        acc.y += v0.y + v1.y;
    }
    if (i < end) {
        float2 v0 = unpackbf2(hw[(long long)csr_src[i] * 64 + lane]);
        acc.x += v0.x;
        acc.y += v0.y;
    }
    float d = dis[node];
    float2 bb = *(const float2*)&b[lane * 2];
    float ox = fmaxf(fmaf(d, acc.x, bb.x), 0.f);
    float oy = fmaxf(fmaf(d, acc.y, bb.y), 0.f);
    out[(long long)node * 64 + lane] = packbf2(ox, oy);
}

// ---------------- FC head (bf16-packed input) ----------------
__launch_bounds__(256)
__global__ void k_fc(const u32* __restrict__ hbf,
                     const float* __restrict__ Wfc,
                     const float* __restrict__ bfc,
                     float* __restrict__ out, int n)
{
    __shared__ float sW[128 * 8];
    __shared__ float sH[32][132];
    const int tid = threadIdx.x;
    *(float4*)&sW[tid * 4] = *(const float4*)&Wfc[tid * 4];
    const int n0 = blockIdx.x * 32;
#pragma unroll
    for (int i = 0; i < 4; i++) {
        int f = tid + i * 256;
        int node = f >> 5;
        int wq = f & 31;
        int gn = n0 + node; if (gn >= n) gn = n - 1;
        uint2 v = *(const uint2*)&hbf[(long long)gn * 64 + wq * 2];
        float2 p0 = unpackbf2(v.x);
        float2 p1 = unpackbf2(v.y);
        sH[node][wq * 4 + 0] = p0.x;
        sH[node][wq * 4 + 1] = p0.y;
        sH[node][wq * 4 + 2] = p1.x;
        sH[node][wq * 4 + 3] = p1.y;
    }
    __syncthreads();
    const int node = tid >> 3;
    const int a = tid & 7;
    float acc = bfc[a];
#pragma unroll
    for (int k = 0; k < 128; k++)
        acc += sH[node][k] * sW[k * 8 + a];
    int gn = n0 + node;
    if (gn < n) out[gn * 8 + a] = acc;
}

extern "C" void kernel_launch(void* const* d_in, const int* in_sizes, int n_in,
                              void* d_out, int out_size, void* d_ws, size_t ws_size,
                              hipStream_t stream) {
    const float* x   = (const float*)d_in[0];
    const int*   ei  = (const int*)d_in[1];
    const float* W1  = (const float*)d_in[2];
    const float* b1  = (const float*)d_in[3];
    const float* W2  = (const float*)d_in[4];
    const float* b2  = (const float*)d_in[5];
    const float* Wfc = (const float*)d_in[6];
    const float* bfc = (const float*)d_in[7];
    float* out = (float*)d_out;

    const int n = NN, e = EE;
    const int nb = (n + 1023) / 1024;

    // workspace layout
    char* ws = (char*)d_ws;
    const size_t MB = 1 << 20;
    float* dis       = (float*)(ws);
    int*   cnt       = (int*)  (ws + 1 * (1 << 19));
    int*   row_start = (int*)  (ws + 2 * (1 << 19));
    int*   cur       = (int*)  (ws + 3 * (1 << 19));
    int*   partial   = (int*)  (ws + 4 * (1 << 19));
    int*   bincnt    = (int*)  (ws + 4 * (1 << 19) + 2048);
    u32*   WT1       = (u32*)  (ws + 5 * (1 << 19));
    u32*   WT2       = (u32*)  (ws + 5 * (1 << 19) + 65536);
    int2*  binbuf    = (int2*) (ws + 3 * MB);                  // 15.36 MB
    int*   csr_src   = (int*)  (ws + 20 * MB);                 // 6.4 MB
    u32*   hwbf      = (u32*)  (ws + 27 * MB);                 // 25.6 MB
    u32*   hbf       = (u32*)  (ws + 53 * MB);                 // 25.6 MB

    const int g256n = (n + 255) / 256;

    // ---- init + W transposes ----
    k_init<<<g256n, 256, 0, stream>>>(cnt, cur, bincnt, n);
    k_wt<<<16, 256, 0, stream>>>(W1, WT1);
    k_wt<<<16, 256, 0, stream>>>(W2, WT2);

    // ---- CSR build + norms ----
    k_bin<<<1280, 256, 0, stream>>>(ei, bincnt, binbuf, cnt, e);
    k_scan_partial<<<nb, 256, 0, stream>>>(cnt, partial, n);
    k_scan_top<<<1, 256, 0, stream>>>(partial, nb);
    k_scan_final<<<nb, 256, 0, stream>>>(cnt, partial, row_start, dis, n);
    k_scatter_bin<<<512, 256, 0, stream>>>(binbuf, bincnt, row_start, cur, csr_src);

    const int gemm_grid = (n + 63) / 64;
    const int agg_grid  = (n + 3) / 4;

    // ---- layer 1 ----
    k_gemm_mfma<1><<<gemm_grid, 256, 0, stream>>>(x, WT1, dis, hwbf, n);
    k_agg<<<agg_grid, 256, 0, stream>>>(csr_src, row_start, hwbf, dis, b1, hbf, n, e);

    // ---- layer 2 ----
    k_gemm_mfma<0><<<gemm_grid, 256, 0, stream>>>(hbf, WT2, dis, hwbf, n);
    k_agg<<<agg_grid, 256, 0, stream>>>(csr_src, row_start, hwbf, dis, b2, hbf, n, e);

    // ---- FC head ----
    k_fc<<<(n + 31) / 32, 256, 0, stream>>>(hbf, Wfc, bfc, out, n);
}